// Round 6
// baseline (186.064 us; speedup 1.0000x reference)
//
#include <hip/hip_runtime.h>
#include <hip/hip_bf16.h>

#define CC 728
#define PP 364          // pairs (even/odd phase length)
#define KP 384          // padded pair-K: 12 * 32
#define M_ROWS 46208    // 32*38*38 = 361 * 128
#define KT 12
#define NWG 2166        // 361 m-tiles * 6 n-tiles (64 pairs each)

typedef __attribute__((ext_vector_type(8))) short bf16x8;
typedef __attribute__((ext_vector_type(4))) float f32x4;

// round-to-nearest-even fp32 -> bf16 bits (host-side table build)
__device__ __forceinline__ unsigned short f2bf(float f) {
    unsigned int u = __float_as_uint(f);
    unsigned int r = u + 0x7fffu + ((u >> 16) & 1u);
    return (unsigned short)(r >> 16);
}

// h[d] for odd d (validated closed form, rounds 1-5):
//   h[d] = s * cos(pi d/728) / (728 sin(pi d/728)),  s = +1 if (d>>1)&1 else -1
// Bt1[n][k] = h[2*((n-k-1) mod 364)+1]   (Ye = 0.5 E + Bt1 . O)
// Bt2[n][k] = h[2*((n-k)   mod 364)+1]   (Yo = 0.5 O + Bt2 . E)
// Both padded to [384][384] bf16, zero outside n<364 && k<364.
__global__ void build_bt(unsigned short* __restrict__ bt1,
                         unsigned short* __restrict__ bt2) {
    int idx = blockIdx.x * blockDim.x + threadIdx.x;
    if (idx >= 2 * KP * KP) return;
    int mat = idx / (KP * KP);
    int rem = idx % (KP * KP);
    int n = rem / KP, k = rem % KP;
    float v = 0.f;
    if (n < PP && k < PP) {
        int m = n - k - (mat == 0 ? 1 : 0);
        if (m < 0) m += PP;
        int d = 2 * m + 1;
        float t = (float)(3.14159265358979323846 * (double)d / (double)CC);
        float s = ((d >> 1) & 1) ? 1.f : -1.f;
        v = s * cosf(t) / ((float)CC * sinf(t));
    }
    (mat == 0 ? bt1 : bt2)[n * KP + k] = f2bf(v);
}

// Zero-LDS, zero-barrier even/odd split GEMM.
// Wave tile: 64 rows x 32 pair-cols (4 m-frags x 2 n-frags x 2 phases).
// Block: 4 waves as 2m x 2n -> 128 rows x 64 pair-cols.
// A-frags loaded directly from global x (fp32) + in-reg cvt_pk to bf16;
// B-frags loaded directly from L2-hot bt tables. Fully-unrolled K-loop
// lets the compiler software-pipeline loads across steps (no vmcnt(0) drains).
__global__ __launch_bounds__(256) void gemm_relu(
        const float* __restrict__ x,
        const unsigned short* __restrict__ bt1,
        const unsigned short* __restrict__ bt2,
        float* __restrict__ out) {
    const int tid  = threadIdx.x;
    const int lane = tid & 63;
    const int wid  = tid >> 6;
    const int wr   = wid >> 1, wc = wid & 1;     // 2x2 wave grid
    const int l15  = lane & 15, lhi = lane >> 4;

    // bijective XCD swizzle (m204); consecutive wgids share an x row-panel (6x)
    const int NX = 8;
    int orig = blockIdx.x;
    int q = NWG / NX, r = NWG % NX;              // 270, 6
    int xcd = orig % NX, local = orig / NX;
    int wgid = (xcd < r ? xcd * (q + 1) : r * (q + 1) + (xcd - r) * q) + local;
    const int bm  = (wgid / 6) * 128;
    const int bnp = (wgid % 6) * 64;             // pair-col base

    f32x4 acc_e[4][2], acc_o[4][2];
#pragma unroll
    for (int i = 0; i < 4; ++i)
#pragma unroll
        for (int j = 0; j < 2; ++j)
#pragma unroll
            for (int rr = 0; rr < 4; ++rr) { acc_e[i][j][rr] = 0.f; acc_o[i][j][rr] = 0.f; }

    // per-lane row bases (constant across K)
    const float* xrow[4];
#pragma unroll
    for (int mi = 0; mi < 4; ++mi)
        xrow[mi] = x + (size_t)(bm + wr * 64 + mi * 16 + l15) * CC;
    const unsigned short* btrow1[2];
    const unsigned short* btrow2[2];
#pragma unroll
    for (int nf = 0; nf < 2; ++nf) {
        int n = bnp + wc * 32 + nf * 16 + l15;
        btrow1[nf] = bt1 + (size_t)n * KP;
        btrow2[nf] = bt2 + (size_t)n * KP;
    }

#pragma unroll
    for (int kt = 0; kt < KT; ++kt) {
        const int pk0 = kt * 32 + lhi * 8;       // pair-k base for this lane
        const int cb0 = kt * 64 + lhi * 16;      // channel base for this lane

        // ---- B fragments: direct 16B loads from L2-hot tables ----
        bf16x8 b1f[2], b2f[2];
#pragma unroll
        for (int nf = 0; nf < 2; ++nf) {
            b1f[nf] = *(const bf16x8*)(btrow1[nf] + pk0);
            b2f[nf] = *(const bf16x8*)(btrow2[nf] + pk0);
        }

        // ---- per m-frag: A load + cvt + MFMA ----
#pragma unroll
        for (int mi = 0; mi < 4; ++mi) {
            float4 f[4];
#pragma unroll
            for (int j = 0; j < 4; ++j) {
                int cb = cb0 + j * 4;            // compile-time foldable guard
                f[j] = (cb < CC) ? ((const float4*)(xrow[mi] + cb0))[j]
                                 : make_float4(0.f, 0.f, 0.f, 0.f);
            }
            union { bf16x8 v; unsigned int u[4]; } aE, aO;
#pragma unroll
            for (int j = 0; j < 4; ++j) {
                asm("v_cvt_pk_bf16_f32 %0, %1, %2"
                    : "=v"(aE.u[j]) : "v"(f[j].x), "v"(f[j].z));
                asm("v_cvt_pk_bf16_f32 %0, %1, %2"
                    : "=v"(aO.u[j]) : "v"(f[j].y), "v"(f[j].w));
            }
#pragma unroll
            for (int nf = 0; nf < 2; ++nf) {
                acc_e[mi][nf] = __builtin_amdgcn_mfma_f32_16x16x32_bf16(
                    aO.v, b1f[nf], acc_e[mi][nf], 0, 0, 0);
                acc_o[mi][nf] = __builtin_amdgcn_mfma_f32_16x16x32_bf16(
                    aE.v, b2f[nf], acc_o[mi][nf], 0, 0, 0);
            }
        }
    }

    // ---- epilogue: +0.5x identity, relu, interleaved float2 store ----
#pragma unroll
    for (int mi = 0; mi < 4; ++mi) {
#pragma unroll
        for (int nf = 0; nf < 2; ++nf) {
            int colp = bnp + wc * 32 + nf * 16 + l15;
            if (colp < PP) {
#pragma unroll
                for (int rr = 0; rr < 4; ++rr) {
                    int rowg = bm + wr * 64 + mi * 16 + lhi * 4 + rr;
                    size_t base = (size_t)rowg * CC + 2 * colp;
                    float2 xv = *(const float2*)&x[base];
                    float2 o;
                    float ye = 0.5f * xv.x + acc_e[mi][nf][rr];
                    float yo = 0.5f * xv.y + acc_o[mi][nf][rr];
                    o.x = ye > 0.f ? ye : 0.f;
                    o.y = yo > 0.f ? yo : 0.f;
                    *(float2*)&out[base] = o;
                }
            }
        }
    }
}

extern "C" void kernel_launch(void* const* d_in, const int* in_sizes, int n_in,
                              void* d_out, int out_size, void* d_ws, size_t ws_size,
                              hipStream_t stream) {
    const float* x = (const float*)d_in[0];
    float* out = (float*)d_out;

    unsigned short* bt1 = (unsigned short*)d_ws;            // 384*384 bf16
    unsigned short* bt2 = bt1 + KP * KP;                    // 384*384 bf16

    build_bt<<<(2 * KP * KP + 255) / 256, 256, 0, stream>>>(bt1, bt2);
    gemm_relu<<<NWG, 256, 0, stream>>>(x, bt1, bt2, out);
}

// Round 7
// 107.752 us; speedup vs baseline: 1.7268x; 1.7268x over previous
//
#include <hip/hip_runtime.h>
#include <hip/hip_bf16.h>

#define CC 728
#define PP 364          // pairs (even/odd phase length)
#define KP 384          // padded pair-K: 12 * 32
#define M_ROWS 46208    // 32*38*38 = 722 * 64
#define KT 12
#define NWG 2166        // 722 m-tiles * 3 pair-n tiles

typedef __attribute__((ext_vector_type(8))) short bf16x8;
typedef __attribute__((ext_vector_type(8))) unsigned short ushort8;
typedef __attribute__((ext_vector_type(4))) float f32x4;

// round-to-nearest-even fp32 -> bf16 bits
__device__ __forceinline__ unsigned short f2bf(float f) {
    unsigned int u = __float_as_uint(f);
    unsigned int r = u + 0x7fffu + ((u >> 16) & 1u);
    return (unsigned short)(r >> 16);
}

__device__ __forceinline__ void gload_lds16(const void* g, void* l) {
    __builtin_amdgcn_global_load_lds(
        (const __attribute__((address_space(1))) void*)g,
        (__attribute__((address_space(3))) void*)l,
        16, 0, 0);
}

// h[d] for odd d (validated closed form, rounds 1-6):
//   h[d] = s * cos(pi d/728) / (728 sin(pi d/728)),  s = +1 if (d>>1)&1 else -1
// Bt1[n][k] = h[2*((n-k-1) mod 364)+1]   (Ye = 0.5 E + Bt1 . O)
// Bt2[n][k] = h[2*((n-k)   mod 364)+1]   (Yo = 0.5 O + Bt2 . E)
// Both padded to [384][384] bf16, zero outside n<364 && k<364.
__global__ void build_bt(unsigned short* __restrict__ bt1,
                         unsigned short* __restrict__ bt2) {
    int idx = blockIdx.x * blockDim.x + threadIdx.x;
    if (idx >= 2 * KP * KP) return;
    int mat = idx / (KP * KP);
    int rem = idx % (KP * KP);
    int n = rem / KP, k = rem % KP;
    float v = 0.f;
    if (n < PP && k < PP) {
        int m = n - k - (mat == 0 ? 1 : 0);
        if (m < 0) m += PP;
        int d = 2 * m + 1;
        float t = (float)(3.14159265358979323846 * (double)d / (double)CC);
        float s = ((d >> 1) & 1) ? 1.f : -1.f;
        v = s * cosf(t) / ((float)CC * sinf(t));
    }
    (mat == 0 ? bt1 : bt2)[n * KP + k] = f2bf(v);
}

// Even/odd split GEMM, 64 rows x 128 pair-cols per block.
// 3-deep LDS buffer rotation + counted vmcnt(8) + raw s_barrier (1/step):
// A(kt+1)/B(kt+1) prefetches stay in flight across the barrier (T4).
//   out[r][2n]   = relu(0.5 x[r][2n]   + sum_k Bt1[n][k] * x[r][2k+1])
//   out[r][2n+1] = relu(0.5 x[r][2n+1] + sum_k Bt2[n][k] * x[r][2k])
__global__ __launch_bounds__(256) void gemm_relu(
        const float* __restrict__ x,
        const unsigned short* __restrict__ bt1,
        const unsigned short* __restrict__ bt2,
        float* __restrict__ out) {
    __shared__ unsigned short ldsE[3][64 * 32];     // 3 x 4 KB
    __shared__ unsigned short ldsO[3][64 * 32];     // 3 x 4 KB
    __shared__ unsigned short ldsB1[3][128 * 32];   // 3 x 8 KB
    __shared__ unsigned short ldsB2[3][128 * 32];   // 3 x 8 KB  => 72 KB total

    const int tid  = threadIdx.x;
    const int lane = tid & 63;
    const int wid  = tid >> 6;
    const int wr   = wid >> 1, wc = wid & 1;     // 2x2 wave grid
    const int l15  = lane & 15, lhi = lane >> 4;

    // bijective XCD swizzle (m204); consecutive wgids share an A row-panel (3x)
    const int NX = 8;
    int orig = blockIdx.x;
    int q = NWG / NX, r = NWG % NX;              // 270, 6
    int xcd = orig % NX, local = orig / NX;
    int wgid = (xcd < r ? xcd * (q + 1) : r * (q + 1) + (xcd - r) * q) + local;
    const int bm  = (wgid / 3) * 64;
    const int bnp = (wgid % 3) * 128;            // pair-col base

    f32x4 acc_e[2][4], acc_o[2][4];
#pragma unroll
    for (int i = 0; i < 2; ++i)
#pragma unroll
        for (int j = 0; j < 4; ++j)
#pragma unroll
            for (int rr = 0; rr < 4; ++rr) { acc_e[i][j][rr] = 0.f; acc_o[i][j][rr] = 0.f; }

    const int brow = tid >> 2;     // B-staging row within 64-row issue
    const int bc   = tid & 3;      // B 8-elem chunk id
    const int arow = tid >> 2;     // A-staging row (0..63)
    const int acx  = tid & 3;      // A 16-channel chunk id

    // ---- staging helpers ----
    auto stageB = [&](int buf, int kt) {        // 4 DMA / thread
        int k0 = kt * 32;
#pragma unroll
        for (int i = 0; i < 2; ++i) {
            int rr   = i * 64 + brow;
            int gsrc = (bc - (rr >> 1)) & 3;
            size_t so = (size_t)(bnp + rr) * KP + k0 + gsrc * 8;
            gload_lds16(bt1 + so, &ldsB1[buf][(i * 256 + tid) * 8]);
            gload_lds16(bt2 + so, &ldsB2[buf][(i * 256 + tid) * 8]);
        }
    };
    auto loadA = [&](int kt, float4* va) {      // 4 reg-loads / thread
        int cb0 = kt * 64 + acx * 16;
        const float* src = x + (size_t)(bm + arow) * CC + cb0;
#pragma unroll
        for (int i = 0; i < 4; ++i)
            va[i] = (cb0 + 4 * i < CC) ? ((const float4*)src)[i]
                                       : make_float4(0.f, 0.f, 0.f, 0.f);
    };
    auto writeA = [&](int buf, const float4* va) {
        ushort8 oe, oo;
#pragma unroll
        for (int p = 0; p < 4; ++p) {
            float4 f = va[p];
            oe[2 * p]     = f2bf(f.x); oo[2 * p]     = f2bf(f.y);
            oe[2 * p + 1] = f2bf(f.z); oo[2 * p + 1] = f2bf(f.w);
        }
        int sc = (acx + (arow >> 1)) & 3;
        *(ushort8*)&ldsE[buf][arow * 32 + sc * 8] = oe;
        *(ushort8*)&ldsO[buf][arow * 32 + sc * 8] = oo;
    };

    // ---- prologue: A(0),B(0),A(1),B(1) in flight ----
    float4 va[2][4];
    loadA(0, va[0]); stageB(0, 0);
    loadA(1, va[1]); stageB(1, 1);

#pragma unroll
    for (int kt = 0; kt < KT; ++kt) {
        const int cur = kt % 3;
        const int nx2 = (kt + 2) % 3;

        // drain A(kt)+B(kt); keep A(kt+1)+B(kt+1) in flight
        asm volatile("s_waitcnt vmcnt(8)" ::: "memory");
        writeA(cur, va[kt & 1]);
        asm volatile("s_waitcnt lgkmcnt(0)" ::: "memory");
        __builtin_amdgcn_s_barrier();
        __builtin_amdgcn_sched_barrier(0);

        // post-barrier: safe to refill buffer (kt+2)%3 (readers done pre-barrier)
        const int kpre = (kt + 2 < KT) ? (kt + 2) : 10;  // clamp: content never read
        loadA(kpre, va[kt & 1]);
        stageB(nx2, kpre);

        // ---- frags + MFMA on buffer cur ----
        bf16x8 aE[2], aO[2], b1[4], b2[4];
#pragma unroll
        for (int mi = 0; mi < 2; ++mi) {
            int row = wr * 32 + mi * 16 + l15;
            int c   = (lhi + (row >> 1)) & 3;
            aE[mi] = *(const bf16x8*)&ldsE[cur][row * 32 + c * 8];
            aO[mi] = *(const bf16x8*)&ldsO[cur][row * 32 + c * 8];
        }
#pragma unroll
        for (int nj = 0; nj < 4; ++nj) {
            int row = wc * 64 + nj * 16 + l15;
            int c   = (lhi + (row >> 1)) & 3;
            b1[nj] = *(const bf16x8*)&ldsB1[cur][row * 32 + c * 8];
            b2[nj] = *(const bf16x8*)&ldsB2[cur][row * 32 + c * 8];
        }
        __builtin_amdgcn_s_setprio(1);
#pragma unroll
        for (int mi = 0; mi < 2; ++mi)
#pragma unroll
            for (int nj = 0; nj < 4; ++nj) {
                acc_e[mi][nj] = __builtin_amdgcn_mfma_f32_16x16x32_bf16(
                    aO[mi], b1[nj], acc_e[mi][nj], 0, 0, 0);
                acc_o[mi][nj] = __builtin_amdgcn_mfma_f32_16x16x32_bf16(
                    aE[mi], b2[nj], acc_o[mi][nj], 0, 0, 0);
            }
        __builtin_amdgcn_s_setprio(0);
    }

    // ---- epilogue: +0.5x identity, relu, interleaved float2 store ----
#pragma unroll
    for (int mi = 0; mi < 2; ++mi) {
#pragma unroll
        for (int nj = 0; nj < 4; ++nj) {
            int colp = bnp + wc * 64 + nj * 16 + l15;
            if (colp < PP) {
#pragma unroll
                for (int rr = 0; rr < 4; ++rr) {
                    int rowg = bm + wr * 32 + mi * 16 + lhi * 4 + rr;
                    size_t base = (size_t)rowg * CC + 2 * colp;
                    float2 xv = *(const float2*)&x[base];
                    float2 o;
                    float ye = 0.5f * xv.x + acc_e[mi][nj][rr];
                    float yo = 0.5f * xv.y + acc_o[mi][nj][rr];
                    o.x = ye > 0.f ? ye : 0.f;
                    o.y = yo > 0.f ? yo : 0.f;
                    *(float2*)&out[base] = o;
                }
            }
        }
    }
}

extern "C" void kernel_launch(void* const* d_in, const int* in_sizes, int n_in,
                              void* d_out, int out_size, void* d_ws, size_t ws_size,
                              hipStream_t stream) {
    const float* x = (const float*)d_in[0];
    float* out = (float*)d_out;

    unsigned short* bt1 = (unsigned short*)d_ws;            // 384*384 bf16
    unsigned short* bt2 = bt1 + KP * KP;                    // 384*384 bf16

    build_bt<<<(2 * KP * KP + 255) / 256, 256, 0, stream>>>(bt1, bt2);
    gemm_relu<<<NWG, 256, 0, stream>>>(x, bt1, bt2, out);
}